// Round 1
// 130.818 us; speedup vs baseline: 1.0424x; 1.0424x over previous
//
#include <hip/hip_runtime.h>
#include <hip/hip_bf16.h>

// B=256, C_IN=6, L=512, C1=32, C2=D=64, NCLASS=10.
// Megakernel v10: in-register softmax. QK is computed SWAPPED
// (mfma(K,Q) instead of mfma(Q,K)), which puts P[q=lc][key=nt*16+quad*4+reg]
// directly in each lane. With V stored under the k-permutation
// k' = quad*8 + rt*4 + reg (same formula applied to P's repack), the exp'd
// scores feed the PV MFMA A-fragment straight from registers: the per-chunk
// Ps LDS round-trip (8 ds_write_b32 + 2 ds_read_b128 per chunk per wave) is
// eliminated entirely. P3c's V store also simplifies to 8 us4 stores.
// Denominator is now per-q=lc; redistributed once in the epilogue via shfl.
// LDS layout/size unchanged (157696 B). ws: prepped weights only.

#define NB 256
#define LL 512
#define CIN 6
#define NCLASS 10
#define SLAB 9472
#define QSC 0.18033688f   // 0.125 * log2(e): exp(s/8) == exp2(s*QSC)

typedef __bf16 bf16x8 __attribute__((ext_vector_type(8)));
typedef float f32x4 __attribute__((ext_vector_type(4)));
typedef unsigned short us4 __attribute__((ext_vector_type(4)));

static __device__ __forceinline__ unsigned short f2b(float f) {
    __bf16 h = (__bf16)f;                       // RNE f32->bf16
    return __builtin_bit_cast(unsigned short, h);
}

// ---------------------------------------------------------------------------
// Kernel P: 1-block weight fold (~2 us).
// w1p[c][k'=dl*8+ci] = w1[c][ci*3+dl]*inv1 (zeros at ci>=6 or dl==3).
// w2p[c2][k'=dl*32+ci]*inv2; b1f/b2f folded; wqp = wq*QSC; wkp; wvp.
// ---------------------------------------------------------------------------
__global__ __launch_bounds__(256) void prep_weights(
    const float* __restrict__ w1, const float* __restrict__ cb1,
    const float* __restrict__ g1, const float* __restrict__ be1,
    const float* __restrict__ m1, const float* __restrict__ v1,
    const float* __restrict__ w2, const float* __restrict__ cb2,
    const float* __restrict__ g2, const float* __restrict__ be2,
    const float* __restrict__ m2, const float* __restrict__ v2,
    const float* __restrict__ wq, const float* __restrict__ wk,
    const float* __restrict__ wv,
    unsigned short* __restrict__ w1p, float* __restrict__ b1f,
    unsigned short* __restrict__ w2p, float* __restrict__ b2f,
    unsigned short* __restrict__ wqp, unsigned short* __restrict__ wkp,
    unsigned short* __restrict__ wvp)
{
    const int t = threadIdx.x;
    for (int idx = t; idx < 1024; idx += 256) {       // w1p [32][32], k'=dl*8+ci
        int c = idx >> 5, k = idx & 31;
        int dl = k >> 3, ci = k & 7;
        float inv = g1[c] * rsqrtf(v1[c] + 1e-5f);
        float val = (dl < 3 && ci < 6) ? w1[c * 18 + ci * 3 + dl] * inv : 0.f;
        w1p[idx] = f2b(val);
    }
    if (t < 32) {
        float inv = g1[t] * rsqrtf(v1[t] + 1e-5f);
        b1f[t] = be1[t] + (cb1[t] - m1[t]) * inv;
    }
    for (int idx = t; idx < 2048; idx += 256) {       // w2p [64][96], k'=dl*32+ci
        int c2 = idx >> 5, ci = idx & 31;
        float inv = g2[c2] * rsqrtf(v2[c2] + 1e-5f);
        const float* wp = w2 + c2 * 96 + ci * 3;
        w2p[c2 * 96 +      ci] = f2b(wp[0] * inv);
        w2p[c2 * 96 + 32 + ci] = f2b(wp[1] * inv);
        w2p[c2 * 96 + 64 + ci] = f2b(wp[2] * inv);
    }
    if (t >= 64 && t < 128) {
        int c2 = t - 64;
        float inv = g2[c2] * rsqrtf(v2[c2] + 1e-5f);
        b2f[c2] = be2[c2] + (cb2[c2] - m2[c2]) * inv;
    }
    for (int idx = t; idx < 4096; idx += 256) {
        wqp[idx] = f2b(wq[idx] * QSC);                // fold 1/8 * log2e
        wkp[idx] = f2b(wk[idx]);
        wvp[idx] = f2b(wv[idx]);
    }
}

// ---------------------------------------------------------------------------
// Megakernel v10. Slabs (9472 B/wave) + xstage (6144 B) = 157696 B LDS.
// Slab phases: conv: h1sl[34][40] @3072 | Ts[32][72] @4608
//              attn: Kf @0 (4096) | Vf @4096 (4096, k'-permuted)
//              epi : redw f32[64] @8192; pooled @ smem+8448
// ---------------------------------------------------------------------------
__global__ __launch_bounds__(1024, 4) void fused_all(
    const float* __restrict__ x,
    const unsigned short* __restrict__ w1p, const float* __restrict__ b1f,
    const unsigned short* __restrict__ w2p, const float* __restrict__ b2f,
    const unsigned short* __restrict__ wqp, const unsigned short* __restrict__ wkp,
    const unsigned short* __restrict__ wvp,
    const float* __restrict__ bq, const float* __restrict__ bk,
    const float* __restrict__ bvp,
    const float* __restrict__ fcw, const float* __restrict__ fcb,
    float* __restrict__ outp)
{
    const int b = blockIdx.x;
    const int t = threadIdx.x;
    const int w = t >> 6, lane = t & 63, quad = lane >> 4, lc = lane & 15;

    __shared__ __align__(16) char smem[16 * SLAB + 6144];   // 157696 B
    char* myslab = smem + w * SLAB;
    unsigned short* h1sl = (unsigned short*)(myslab + 3072);
    unsigned short* Ts   = (unsigned short*)(myslab + 4608);
    unsigned short* Kf   = (unsigned short*)myslab;
    unsigned short* Vf   = (unsigned short*)(myslab + 4096);
    float* redw   = (float*)(myslab + 8192);         // epilogue scratch
    float* pooled = (float*)(smem + 8448);           // slab0, after wave0 redw
    unsigned short* xstage = (unsigned short*)(smem + 16 * SLAB);  // [6][512]

    // ---- P0: stage x[b] as bf16 into block LDS (coalesced) ---------------
    if (t < 768) {
        int ci = t >> 7, j4 = (t & 127) * 4;
        float4 xv = *(const float4*)(x + ((size_t)b * CIN + ci) * LL + j4);
        us4 pk;
        pk[0] = f2b(xv.x); pk[1] = f2b(xv.y); pk[2] = f2b(xv.z); pk[3] = f2b(xv.w);
        *(us4*)&xstage[ci * 512 + j4] = pk;
    }
    __syncthreads();

    // ---- P1: conv1 as MFMA; A-frags gathered from xstage -----------------
    // k'=dl*8+ci: frag elem u -> ci=u, dl=quad; pos shared across u.
    bf16x8 bW1[2];
    #pragma unroll
    for (int nt = 0; nt < 2; nt++)
        bW1[nt] = *(const bf16x8*)(w1p + (nt * 16 + lc) * 32 + quad * 8);
    float b1v[2] = {b1f[lc], b1f[16 + lc]};
    f32x4 h1acc[3][2];
    #pragma unroll
    for (int mt = 0; mt < 3; mt++) {
        int pos = w * 32 - 2 + mt * 16 + lc + quad;
        bool ok = (quad < 3) && (pos >= 0) && (pos < LL);
        int posc = pos < 0 ? 0 : (pos > 511 ? 511 : pos);
        bf16x8 aX;
        #pragma unroll
        for (int u = 0; u < 6; u++) {
            __bf16 vb = __builtin_bit_cast(__bf16, xstage[u * 512 + posc]);
            aX[u] = ok ? vb : (__bf16)0.f;
        }
        aX[6] = (__bf16)0.f; aX[7] = (__bf16)0.f;
        #pragma unroll
        for (int nt = 0; nt < 2; nt++) {
            f32x4 z = {0.f, 0.f, 0.f, 0.f};
            h1acc[mt][nt] = __builtin_amdgcn_mfma_f32_16x16x32_bf16(aX, bW1[nt], z, 0, 0, 0);
        }
    }
    #pragma unroll
    for (int mt = 0; mt < 3; mt++)
        #pragma unroll
        for (int nt = 0; nt < 2; nt++)
            #pragma unroll
            for (int r = 0; r < 4; r++) {
                int j = mt * 16 + quad * 4 + r;
                if (j < 34) {
                    int pos = w * 32 - 1 + j;
                    float y = h1acc[mt][nt][r] + b1v[nt];
                    y = (pos >= 0 && pos < LL && y > 0.f) ? y : 0.f;
                    h1sl[j * 40 + nt * 16 + lc] = f2b(y);
                }
            }

    // ---- P2: conv2 as GEMM (M=64 c2, N=32 rows, K=96; k'=dl*32+ci) -------
    bf16x8 bX[2][3], aW2[4][3];
    #pragma unroll
    for (int rt = 0; rt < 2; rt++)
        #pragma unroll
        for (int kc = 0; kc < 3; kc++)
            bX[rt][kc] = *(const bf16x8*)&h1sl[(rt * 16 + lc + kc) * 40 + quad * 8];
    #pragma unroll
    for (int nt = 0; nt < 4; nt++)
        #pragma unroll
        for (int kc = 0; kc < 3; kc++)
            aW2[nt][kc] = *(const bf16x8*)(w2p + (nt * 16 + lc) * 96 + kc * 32 + quad * 8);

    f32x4 acc2[4][2];
    #pragma unroll
    for (int nt = 0; nt < 4; nt++)
        #pragma unroll
        for (int rt = 0; rt < 2; rt++) {
            f32x4 a = {0.f, 0.f, 0.f, 0.f};
            a = __builtin_amdgcn_mfma_f32_16x16x32_bf16(aW2[nt][0], bX[rt][0], a, 0, 0, 0);
            a = __builtin_amdgcn_mfma_f32_16x16x32_bf16(aW2[nt][1], bX[rt][1], a, 0, 0, 0);
            acc2[nt][rt] = __builtin_amdgcn_mfma_f32_16x16x32_bf16(aW2[nt][2], bX[rt][2], a, 0, 0, 0);
        }

    // ---- P3a: +b2f, relu -> Ts[row][c2] ----------------------------------
    #pragma unroll
    for (int nt = 0; nt < 4; nt++) {
        const float4 bb2 = *(const float4*)&b2f[nt * 16 + quad * 4];
        #pragma unroll
        for (int rt = 0; rt < 2; rt++) {
            us4 pk;
            float y0 = acc2[nt][rt][0] + bb2.x; pk[0] = f2b(y0 > 0.f ? y0 : 0.f);
            float y1 = acc2[nt][rt][1] + bb2.y; pk[1] = f2b(y1 > 0.f ? y1 : 0.f);
            float y2 = acc2[nt][rt][2] + bb2.z; pk[2] = f2b(y2 > 0.f ? y2 : 0.f);
            float y3 = acc2[nt][rt][3] + bb2.w; pk[3] = f2b(y3 > 0.f ? y3 : 0.f);
            *(us4*)&Ts[(rt * 16 + lc) * 72 + nt * 16 + quad * 4] = pk;
        }
    }
    bf16x8 aH[2][2];
    #pragma unroll
    for (int rt = 0; rt < 2; rt++)
        #pragma unroll
        for (int kc = 0; kc < 2; kc++)
            aH[rt][kc] = *(const bf16x8*)&Ts[(rt * 16 + lc) * 72 + kc * 32 + quad * 8];

    // ---- P3b: q (regs, QSC-scaled) then k (straight into slab Kf) --------
    bf16x8 aQ[2][2];
    for (int p = 0; p < 2; p++) {
        const unsigned short* wsrc = p ? wkp : wqp;
        const float* bsrc = p ? bk : bq;
        const float bscl = p ? 1.0f : QSC;
        #pragma unroll
        for (int nt = 0; nt < 4; nt++) {
            bf16x8 aW[2];
            #pragma unroll
            for (int kc = 0; kc < 2; kc++)
                aW[kc] = *(const bf16x8*)(wsrc + (nt * 16 + lc) * 64 + kc * 32 + quad * 8);
            float4 bb = *(const float4*)&bsrc[nt * 16 + quad * 4];
            bb.x *= bscl; bb.y *= bscl; bb.z *= bscl; bb.w *= bscl;
            #pragma unroll
            for (int rt = 0; rt < 2; rt++) {
                f32x4 a = {0.f, 0.f, 0.f, 0.f};
                a = __builtin_amdgcn_mfma_f32_16x16x32_bf16(aW[0], aH[rt][0], a, 0, 0, 0);
                a = __builtin_amdgcn_mfma_f32_16x16x32_bf16(aW[1], aH[rt][1], a, 0, 0, 0);
                us4 pk;
                pk[0] = f2b(a[0] + bb.x); pk[1] = f2b(a[1] + bb.y);
                pk[2] = f2b(a[2] + bb.z); pk[3] = f2b(a[3] + bb.w);
                *(us4*)&Ts[(rt * 16 + lc) * 72 + nt * 16 + quad * 4] = pk;
            }
        }
        #pragma unroll
        for (int rt = 0; rt < 2; rt++)
            #pragma unroll
            for (int kc = 0; kc < 2; kc++) {
                bf16x8 fr = *(const bf16x8*)&Ts[(rt * 16 + lc) * 72 + kc * 32 + quad * 8];
                if (p == 0) aQ[rt][kc] = fr;
                else *(bf16x8*)&Kf[((rt * 2 + kc) << 9) + lane * 8] = fr;
            }
    }

    // ---- P3c: v -> Vf, k'-PERMUTED to match the in-register P repack -----
    // C elem: key = rt*16 + quad*4 + reg, d = nt*16 + lc.
    // k' = quad*8 + rt*4 + reg  ->  store addr nt*512 + (k'>>3)*128 + lc*8
    // + (k'&7): the 4 regs are CONSECUTIVE -> one us4 store per (nt,rt).
    #pragma unroll
    for (int nt = 0; nt < 4; nt++) {
        bf16x8 bW[2];
        #pragma unroll
        for (int kc = 0; kc < 2; kc++)
            bW[kc] = *(const bf16x8*)(wvp + (nt * 16 + lc) * 64 + kc * 32 + quad * 8);
        const float bvv = bvp[nt * 16 + lc];
        #pragma unroll
        for (int rt = 0; rt < 2; rt++) {
            f32x4 a = {0.f, 0.f, 0.f, 0.f};
            a = __builtin_amdgcn_mfma_f32_16x16x32_bf16(aH[rt][0], bW[0], a, 0, 0, 0);
            a = __builtin_amdgcn_mfma_f32_16x16x32_bf16(aH[rt][1], bW[1], a, 0, 0, 0);
            us4 pk;
            pk[0] = f2b(a[0] + bvv); pk[1] = f2b(a[1] + bvv);
            pk[2] = f2b(a[2] + bvv); pk[3] = f2b(a[3] + bvv);
            *(us4*)&Vf[nt * 512 + quad * 128 + lc * 8 + rt * 4] = pk;
        }
    }

    __syncthreads();          // all waves' Kf/Vf ready — only pre-attn barrier

    // ---- attention: single pass, 16 chunks, in-register softmax ----------
    // sv[nt][rt] = mfma(K, Q): lane holds P[q=lc][key = nt*16+quad*4+reg].
    // exp2 + bf16-cast repacks straight into PV A-frag elem e = nt*4+reg
    // (k' = quad*8 + e, matching Vf's permutation). No Ps LDS round-trip.
    f32x4 outacc[2][4];
    #pragma unroll
    for (int rt = 0; rt < 2; rt++)
        #pragma unroll
        for (int dt = 0; dt < 4; dt++) outacc[rt][dt] = (f32x4){0.f, 0.f, 0.f, 0.f};
    float den[2] = {0.f, 0.f};

    bf16x8 bK[2][2], bKn[2][2];
    {
        const unsigned short* sK = (const unsigned short*)smem;   // chunk 0
        #pragma unroll
        for (int nt = 0; nt < 2; nt++)
            #pragma unroll
            for (int kc = 0; kc < 2; kc++)
                bK[nt][kc] = *(const bf16x8*)&sK[((nt * 2 + kc) << 9) + lane * 8];
    }

    for (int cc = 0; cc < 16; cc++) {
        f32x4 sv[2][2];                               // [nt][rt]
        #pragma unroll
        for (int nt = 0; nt < 2; nt++)
            #pragma unroll
            for (int rt = 0; rt < 2; rt++) {
                f32x4 z = {0.f, 0.f, 0.f, 0.f};
                z = __builtin_amdgcn_mfma_f32_16x16x32_bf16(bK[nt][0], aQ[rt][0], z, 0, 0, 0);
                sv[nt][rt] = __builtin_amdgcn_mfma_f32_16x16x32_bf16(bK[nt][1], aQ[rt][1], z, 0, 0, 0);
            }
        const unsigned short* sV = (const unsigned short*)(smem + cc * SLAB + 4096);
        bf16x8 bV[4];
        #pragma unroll
        for (int dt = 0; dt < 4; dt++)
            bV[dt] = *(const bf16x8*)&sV[dt * 512 + lane * 8];
        if (cc < 15) {                                // prefetch next K frags
            const unsigned short* sKn = (const unsigned short*)(smem + (cc + 1) * SLAB);
            #pragma unroll
            for (int nt = 0; nt < 2; nt++)
                #pragma unroll
                for (int kc = 0; kc < 2; kc++)
                    bKn[nt][kc] = *(const bf16x8*)&sKn[((nt * 2 + kc) << 9) + lane * 8];
        }
        bf16x8 aP[2];
        #pragma unroll
        for (int rt = 0; rt < 2; rt++)
            #pragma unroll
            for (int nt = 0; nt < 2; nt++)
                #pragma unroll
                for (int reg = 0; reg < 4; reg++) {
                    float p = __builtin_amdgcn_exp2f(sv[nt][rt][reg]);
                    den[rt] += p;
                    aP[rt][nt * 4 + reg] = (__bf16)p;
                }
        #pragma unroll
        for (int dt = 0; dt < 4; dt++) {
            outacc[0][dt] = __builtin_amdgcn_mfma_f32_16x16x32_bf16(aP[0], bV[dt], outacc[0][dt], 0, 0, 0);
            outacc[1][dt] = __builtin_amdgcn_mfma_f32_16x16x32_bf16(aP[1], bV[dt], outacc[1][dt], 0, 0, 0);
        }
        #pragma unroll
        for (int nt = 0; nt < 2; nt++)
            #pragma unroll
            for (int kc = 0; kc < 2; kc++)
                bK[nt][kc] = bKn[nt][kc];
    }

    // ---- epilogue: den reduce (per q=lc, sum over quads), redistribute ---
    // den[rt] holds 8 keys' partials for q=lc; xor16+xor32 completes the
    // 512-key sum; shfl moves 1/den to the outacc row layout q=quad*4+reg.
    float rden[2][4];
    #pragma unroll
    for (int rt = 0; rt < 2; rt++) {
        float d2 = den[rt];
        d2 += __shfl_xor(d2, 16);
        d2 += __shfl_xor(d2, 32);
        d2 = 1.0f / d2;
        #pragma unroll
        for (int reg = 0; reg < 4; reg++)
            rden[rt][reg] = __shfl(d2, quad * 4 + reg);
    }
    #pragma unroll
    for (int dt = 0; dt < 4; dt++) {
        float ps = 0.f;
        #pragma unroll
        for (int rt = 0; rt < 2; rt++)
            #pragma unroll
            for (int reg = 0; reg < 4; reg++)
                ps += outacc[rt][dt][reg] * rden[rt][reg];
        ps += __shfl_xor(ps, 16);
        ps += __shfl_xor(ps, 32);
        if (quad == 0) redw[dt * 16 + lc] = ps;
    }
    __syncthreads();
    if (t < 64) {
        float s = 0.f;
        #pragma unroll
        for (int ww = 0; ww < 16; ww++)
            s += *(const float*)(smem + ww * SLAB + 8192 + t * 4);
        pooled[t] = s * (1.0f / 512.0f);
    }
    __syncthreads();
    if (t < NCLASS) {
        float acc = fcb[t];
        #pragma unroll
        for (int d = 0; d < 64; d++) acc += pooled[d] * fcw[t * 64 + d];
        outp[b * NCLASS + t] = acc;
    }
}

// ---------------------------------------------------------------------------
extern "C" void kernel_launch(void* const* d_in, const int* in_sizes, int n_in,
                              void* d_out, int out_size, void* d_ws, size_t ws_size,
                              hipStream_t stream)
{
    const float* x   = (const float*)d_in[0];
    const float* w1  = (const float*)d_in[1];
    const float* cb1 = (const float*)d_in[2];
    const float* g1  = (const float*)d_in[3];
    const float* be1 = (const float*)d_in[4];
    const float* m1  = (const float*)d_in[5];
    const float* v1  = (const float*)d_in[6];
    const float* w2  = (const float*)d_in[7];
    const float* cb2 = (const float*)d_in[8];
    const float* g2  = (const float*)d_in[9];
    const float* be2 = (const float*)d_in[10];
    const float* m2  = (const float*)d_in[11];
    const float* v2  = (const float*)d_in[12];
    const float* wq  = (const float*)d_in[13];
    const float* bq  = (const float*)d_in[14];
    const float* wk  = (const float*)d_in[15];
    const float* bk  = (const float*)d_in[16];
    const float* wv  = (const float*)d_in[17];
    const float* bv  = (const float*)d_in[18];
    const float* fcw = (const float*)d_in[19];
    const float* fcb = (const float*)d_in[20];
    float* out = (float*)d_out;

    char* ws = (char*)d_ws;
    unsigned short* w1p = (unsigned short*)(ws);            // 2048 B
    float*          b1f = (float*)(ws + 2048u);             // 128 B
    float*          b2f = (float*)(ws + 2176u);             // 256 B
    unsigned short* w2p = (unsigned short*)(ws + 2432u);    // 12288 B
    unsigned short* wqp = (unsigned short*)(ws + 14720u);   // 8192 B
    unsigned short* wkp = (unsigned short*)(ws + 22912u);   // 8192 B
    unsigned short* wvp = (unsigned short*)(ws + 31104u);   // 8192 B

    prep_weights<<<dim3(1), 256, 0, stream>>>(w1, cb1, g1, be1, m1, v1,
                                              w2, cb2, g2, be2, m2, v2,
                                              wq, wk, wv,
                                              w1p, b1f, w2p, b2f, wqp, wkp, wvp);
    fused_all<<<dim3(NB), 1024, 0, stream>>>(x, w1p, b1f, w2p, b2f,
                                             wqp, wkp, wvp,
                                             bq, bk, bv, fcw, fcb, out);
}

// Round 2
// 130.000 us; speedup vs baseline: 1.0489x; 1.0063x over previous
//
#include <hip/hip_runtime.h>
#include <hip/hip_bf16.h>

// B=256, C_IN=6, L=512, C1=32, C2=D=64, NCLASS=10.
// Megakernel v11: permuted-contraction everywhere + pipelined attn.
//  - sigma_h (channel contraction of q/k/v): baked into wqp/wkp/wvp at prep,
//    aH assembled in-register from conv2 acc -> Ts buffer ELIMINATED.
//  - sigma_d (d contraction of QK): aQ packed in-register from q-MFMA C regs
//    (Q never touches LDS); Kf stored in frag order as 4 x b128.
//  - key-perm for PV (v10's trick): Vf stored as 4 x b128.
//  - conv1 swapped (mfma(W1,X)) + xstage transposed to [pos][ch]: A-gather is
//    3 x ds_read_b128 (was 18 ds_read_u16), h1 store 6 x us4 (was 24 u16).
//  - attn software-pipelined by 1 chunk: exp(sv_prev) overlaps ds loads,
//    QK(cc+1) issued after PV (never waited on); bK double-buffer dropped;
//    s_setprio(1) around the 16-MFMA cluster.
// LDS 139264 B (16 x 8192 slab + 8192 xstage). ws: prepped weights only.

#define NB 256
#define LL 512
#define CIN 6
#define NCLASS 10
#define SLAB 8192
#define QSC 0.18033688f   // 0.125 * log2(e): exp(s/8) == exp2(s*QSC)

typedef __bf16 bf16x8 __attribute__((ext_vector_type(8)));
typedef float f32x4 __attribute__((ext_vector_type(4)));
typedef unsigned short us4 __attribute__((ext_vector_type(4)));
typedef unsigned short us8 __attribute__((ext_vector_type(8)));
typedef unsigned int u32x4 __attribute__((ext_vector_type(4)));

static __device__ __forceinline__ unsigned short f2b(float f) {
    __bf16 h = (__bf16)f;                       // RNE f32->bf16
    return __builtin_bit_cast(unsigned short, h);
}

// ---------------------------------------------------------------------------
// Kernel P: 1-block weight fold (~2 us).
// w1p[c][k'=dl*8+ci] = w1[c][ci*3+dl]*inv1 (zeros at ci>=6 or dl==3).
// w2p[c2][k'=dl*32+ci]*inv2; b1f/b2f folded.
// wqp/wkp/wvp laid out with sigma_h on the channel (contraction) dim:
//   slot k' (kc=k'>>5, quad=(k'>>3)&3, e=k'&7) <- ch = kc*32+(e>>2)*16+quad*4+(e&3)
// ---------------------------------------------------------------------------
__global__ __launch_bounds__(256) void prep_weights(
    const float* __restrict__ w1, const float* __restrict__ cb1,
    const float* __restrict__ g1, const float* __restrict__ be1,
    const float* __restrict__ m1, const float* __restrict__ v1,
    const float* __restrict__ w2, const float* __restrict__ cb2,
    const float* __restrict__ g2, const float* __restrict__ be2,
    const float* __restrict__ m2, const float* __restrict__ v2,
    const float* __restrict__ wq, const float* __restrict__ wk,
    const float* __restrict__ wv,
    unsigned short* __restrict__ w1p, float* __restrict__ b1f,
    unsigned short* __restrict__ w2p, float* __restrict__ b2f,
    unsigned short* __restrict__ wqp, unsigned short* __restrict__ wkp,
    unsigned short* __restrict__ wvp)
{
    const int t = threadIdx.x;
    for (int idx = t; idx < 1024; idx += 256) {       // w1p [32][32], k'=dl*8+ci
        int c = idx >> 5, k = idx & 31;
        int dl = k >> 3, ci = k & 7;
        float inv = g1[c] * rsqrtf(v1[c] + 1e-5f);
        float val = (dl < 3 && ci < 6) ? w1[c * 18 + ci * 3 + dl] * inv : 0.f;
        w1p[idx] = f2b(val);
    }
    if (t < 32) {
        float inv = g1[t] * rsqrtf(v1[t] + 1e-5f);
        b1f[t] = be1[t] + (cb1[t] - m1[t]) * inv;
    }
    for (int idx = t; idx < 2048; idx += 256) {       // w2p [64][96], k'=dl*32+ci
        int c2 = idx >> 5, ci = idx & 31;
        float inv = g2[c2] * rsqrtf(v2[c2] + 1e-5f);
        const float* wp = w2 + c2 * 96 + ci * 3;
        w2p[c2 * 96 +      ci] = f2b(wp[0] * inv);
        w2p[c2 * 96 + 32 + ci] = f2b(wp[1] * inv);
        w2p[c2 * 96 + 64 + ci] = f2b(wp[2] * inv);
    }
    if (t >= 64 && t < 128) {
        int c2 = t - 64;
        float inv = g2[c2] * rsqrtf(v2[c2] + 1e-5f);
        b2f[c2] = be2[c2] + (cb2[c2] - m2[c2]) * inv;
    }
    for (int idx = t; idx < 4096; idx += 256) {       // sigma_h permuted
        int d = idx >> 6, k = idx & 63;
        int kc = k >> 5, quad = (k >> 3) & 3, e = k & 7;
        int ch = kc * 32 + (e >> 2) * 16 + quad * 4 + (e & 3);
        wqp[idx] = f2b(wq[d * 64 + ch] * QSC);        // fold 1/8 * log2e
        wkp[idx] = f2b(wk[d * 64 + ch]);
        wvp[idx] = f2b(wv[d * 64 + ch]);
    }
}

// ---------------------------------------------------------------------------
// Megakernel v11. LDS: 16 slabs x 8192 B + xstage 8192 B = 139264 B.
// Slab phases: conv: h1sl[34][40] @0 (2720 B, dead before Kf written)
//              attn: Kf @0 (4096) | Vf @4096 (4096, key-permuted, frag order)
// xstage [512][8] u16 (transposed, dead after P1); epilogue redw/pooled
// live in the xstage region (no extra barrier needed).
// ---------------------------------------------------------------------------
__global__ __launch_bounds__(1024, 4) void fused_all(
    const float* __restrict__ x,
    const unsigned short* __restrict__ w1p, const float* __restrict__ b1f,
    const unsigned short* __restrict__ w2p, const float* __restrict__ b2f,
    const unsigned short* __restrict__ wqp, const unsigned short* __restrict__ wkp,
    const unsigned short* __restrict__ wvp,
    const float* __restrict__ bq, const float* __restrict__ bk,
    const float* __restrict__ bvp,
    const float* __restrict__ fcw, const float* __restrict__ fcb,
    float* __restrict__ outp)
{
    const int b = blockIdx.x;
    const int t = threadIdx.x;
    const int w = t >> 6, lane = t & 63, quad = lane >> 4, lc = lane & 15;

    __shared__ __align__(16) char smem[16 * SLAB + 8192];   // 139264 B
    char* myslab = smem + w * SLAB;
    unsigned short* h1sl = (unsigned short*)myslab;          // [34][40] conv scratch
    unsigned short* Kf   = (unsigned short*)myslab;          // attn, frag order
    unsigned short* Vf   = (unsigned short*)(myslab + 4096); // attn, frag order
    unsigned short* xstage = (unsigned short*)(smem + 16 * SLAB);  // [512][8]
    float* redw   = (float*)(smem + 16 * SLAB) + w * 64;     // epilogue (xstage dead)
    float* pooled = (float*)(smem + 16 * SLAB + 4096);

    // ---- P0: stage x[b] transposed to [pos][ch(8)] bf16 (b128 rows) ------
    if (t < 512) {
        us8 pk;
        #pragma unroll
        for (int ci = 0; ci < 6; ci++)
            pk[ci] = f2b(x[((size_t)b * CIN + ci) * LL + t]);  // coalesced per ci
        pk[6] = 0; pk[7] = 0;
        *(us8*)&xstage[t * 8] = pk;
    }
    __syncthreads();

    // ---- P1: conv1 swapped: h1 = mfma(W1, X). ----------------------------
    // A=bW1: row=ch (nt*16+lc), k'=dl*8+ci (dl=quad, ci=e) — w1p layout.
    // B=aX : col=pos (j=mt*16+lc), same k' — one b128 from xstage[src].
    // C: row=ch=nt*16+quad*4+r, col=j -> h1sl[j][ch] as us4 stores.
    bf16x8 bW1[2];
    #pragma unroll
    for (int nt = 0; nt < 2; nt++)
        bW1[nt] = *(const bf16x8*)(w1p + (nt * 16 + lc) * 32 + quad * 8);
    f32x4 b1q[2];
    #pragma unroll
    for (int nt = 0; nt < 2; nt++)
        b1q[nt] = *(const f32x4*)&b1f[nt * 16 + quad * 4];
    #pragma unroll
    for (int mt = 0; mt < 3; mt++) {
        int j = mt * 16 + lc;                 // 0..47, keep <34
        int P = w * 32 - 1 + j;               // output position (halo +-1)
        int src = P + quad - 1;               // x position for dl=quad
        bool okx = (src >= 0) && (src < LL);  // quad==3 -> weight is zero anyway
        int srcc = src < 0 ? 0 : (src > 511 ? 511 : src);
        u32x4 xv = *(const u32x4*)&xstage[srcc * 8];
        if (!okx) { xv[0] = 0u; xv[1] = 0u; xv[2] = 0u; xv[3] = 0u; }
        bf16x8 aX = __builtin_bit_cast(bf16x8, xv);
        bool pv = (P >= 0) && (P < LL);
        #pragma unroll
        for (int nt = 0; nt < 2; nt++) {
            f32x4 z = {0.f, 0.f, 0.f, 0.f};
            f32x4 h = __builtin_amdgcn_mfma_f32_16x16x32_bf16(bW1[nt], aX, z, 0, 0, 0);
            us4 pk;
            #pragma unroll
            for (int r = 0; r < 4; r++) {
                float y = h[r] + b1q[nt][r];
                y = (pv && y > 0.f) ? y : 0.f;
                pk[r] = f2b(y);
            }
            if (j < 34)
                *(us4*)&h1sl[j * 40 + nt * 16 + quad * 4] = pk;
        }
    }

    // ---- P2: conv2 as GEMM (M=64 c2, N=32 rows, K=96; k'=dl*32+ci) -------
    bf16x8 bX[2][3], aW2[4][3];
    #pragma unroll
    for (int rt = 0; rt < 2; rt++)
        #pragma unroll
        for (int kc = 0; kc < 3; kc++)
            bX[rt][kc] = *(const bf16x8*)&h1sl[(rt * 16 + lc + kc) * 40 + quad * 8];
    #pragma unroll
    for (int nt = 0; nt < 4; nt++)
        #pragma unroll
        for (int kc = 0; kc < 3; kc++)
            aW2[nt][kc] = *(const bf16x8*)(w2p + (nt * 16 + lc) * 96 + kc * 32 + quad * 8);

    f32x4 acc2[4][2];
    #pragma unroll
    for (int nt = 0; nt < 4; nt++)
        #pragma unroll
        for (int rt = 0; rt < 2; rt++) {
            f32x4 a = {0.f, 0.f, 0.f, 0.f};
            a = __builtin_amdgcn_mfma_f32_16x16x32_bf16(aW2[nt][0], bX[rt][0], a, 0, 0, 0);
            a = __builtin_amdgcn_mfma_f32_16x16x32_bf16(aW2[nt][1], bX[rt][1], a, 0, 0, 0);
            acc2[nt][rt] = __builtin_amdgcn_mfma_f32_16x16x32_bf16(aW2[nt][2], bX[rt][2], a, 0, 0, 0);
        }

    // ---- P3a: +b2f, relu -> aH in REGISTERS (sigma_h frag order) ---------
    // aH[rt][kc][e] = h[ch = 32kc+16(e>>2)+4quad+(e&3)][pos=rt*16+lc]
    //              = relu(acc2[nt2=2kc+(e>>2)][rt][e&3] + b2f).
    bf16x8 aH[2][2];
    #pragma unroll
    for (int nt2 = 0; nt2 < 4; nt2++) {
        f32x4 bb2 = *(const f32x4*)&b2f[nt2 * 16 + quad * 4];
        #pragma unroll
        for (int rt = 0; rt < 2; rt++)
            #pragma unroll
            for (int reg = 0; reg < 4; reg++) {
                float y = acc2[nt2][rt][reg] + bb2[reg];
                aH[rt][nt2 >> 1][(nt2 & 1) * 4 + reg] = (__bf16)(y > 0.f ? y : 0.f);
            }
    }

    // ---- P3b: q fully in registers; k -> Kf as 4 x b128 (sigma_d order) --
    // C elem (nt,rt,reg) holds val[d=nt*16+quad*4+reg][pos/key=rt*16+lc].
    // Frag slot (kc,e): nt = 2kc+(e>>2), reg = e&3  (sigma_d on d).
    bf16x8 aQ[2][2];
    {
        f32x4 Cq[4][2], bbq[4];
        #pragma unroll
        for (int nt = 0; nt < 4; nt++) {
            bf16x8 aW0 = *(const bf16x8*)(wqp + (nt * 16 + lc) * 64 + quad * 8);
            bf16x8 aW1 = *(const bf16x8*)(wqp + (nt * 16 + lc) * 64 + 32 + quad * 8);
            bbq[nt] = *(const f32x4*)&bq[nt * 16 + quad * 4];
            #pragma unroll
            for (int rt = 0; rt < 2; rt++) {
                f32x4 a = {0.f, 0.f, 0.f, 0.f};
                a = __builtin_amdgcn_mfma_f32_16x16x32_bf16(aW0, aH[rt][0], a, 0, 0, 0);
                Cq[nt][rt] = __builtin_amdgcn_mfma_f32_16x16x32_bf16(aW1, aH[rt][1], a, 0, 0, 0);
            }
        }
        #pragma unroll
        for (int rt = 0; rt < 2; rt++)
            #pragma unroll
            for (int nt = 0; nt < 4; nt++)
                #pragma unroll
                for (int reg = 0; reg < 4; reg++)
                    aQ[rt][nt >> 1][(nt & 1) * 4 + reg] =
                        (__bf16)(Cq[nt][rt][reg] + bbq[nt][reg] * QSC);
    }
    {
        f32x4 Ck[4][2], bbk[4];
        #pragma unroll
        for (int nt = 0; nt < 4; nt++) {
            bf16x8 aW0 = *(const bf16x8*)(wkp + (nt * 16 + lc) * 64 + quad * 8);
            bf16x8 aW1 = *(const bf16x8*)(wkp + (nt * 16 + lc) * 64 + 32 + quad * 8);
            bbk[nt] = *(const f32x4*)&bk[nt * 16 + quad * 4];
            #pragma unroll
            for (int rt = 0; rt < 2; rt++) {
                f32x4 a = {0.f, 0.f, 0.f, 0.f};
                a = __builtin_amdgcn_mfma_f32_16x16x32_bf16(aW0, aH[rt][0], a, 0, 0, 0);
                Ck[nt][rt] = __builtin_amdgcn_mfma_f32_16x16x32_bf16(aW1, aH[rt][1], a, 0, 0, 0);
            }
        }
        #pragma unroll
        for (int rt = 0; rt < 2; rt++)
            #pragma unroll
            for (int kc = 0; kc < 2; kc++) {
                us8 pk;
                #pragma unroll
                for (int e = 0; e < 8; e++) {
                    int nt = kc * 2 + (e >> 2), reg = e & 3;
                    pk[e] = f2b(Ck[nt][rt][reg] + bbk[nt][reg]);
                }
                *(us8*)&Kf[((rt * 2 + kc) << 9) + lane * 8] = pk;
            }
    }

    // ---- P3c: v -> Vf as 4 x b128 (key-permuted frag order, as v10) ------
    // C elem (nt,rtV,reg): val[key=rtV*16+quad*4+reg][d=nt*16+lc];
    // frag elem e = rtV*4+reg  ->  k' = quad*8+e.
    #pragma unroll
    for (int nt = 0; nt < 4; nt++) {
        bf16x8 bW0 = *(const bf16x8*)(wvp + (nt * 16 + lc) * 64 + quad * 8);
        bf16x8 bW1 = *(const bf16x8*)(wvp + (nt * 16 + lc) * 64 + 32 + quad * 8);
        const float bvv = bvp[nt * 16 + lc];
        f32x4 a0, a1;
        {
            f32x4 z = {0.f, 0.f, 0.f, 0.f};
            z = __builtin_amdgcn_mfma_f32_16x16x32_bf16(aH[0][0], bW0, z, 0, 0, 0);
            a0 = __builtin_amdgcn_mfma_f32_16x16x32_bf16(aH[0][1], bW1, z, 0, 0, 0);
        }
        {
            f32x4 z = {0.f, 0.f, 0.f, 0.f};
            z = __builtin_amdgcn_mfma_f32_16x16x32_bf16(aH[1][0], bW0, z, 0, 0, 0);
            a1 = __builtin_amdgcn_mfma_f32_16x16x32_bf16(aH[1][1], bW1, z, 0, 0, 0);
        }
        us8 pk;
        #pragma unroll
        for (int reg = 0; reg < 4; reg++) {
            pk[reg]     = f2b(a0[reg] + bvv);
            pk[4 + reg] = f2b(a1[reg] + bvv);
        }
        *(us8*)&Vf[nt * 512 + lane * 8] = pk;
    }

    __syncthreads();          // all waves' Kf/Vf ready — only pre-attn barrier

    // ---- attention: 16 chunks, in-register softmax, pipelined by 1 -------
    // sv holds QK(cc) results computed at the END of iteration cc-1 (or the
    // prologue), so exp never waits on a just-issued MFMA; QK(cc+1) consumes
    // bK2 loaded this iteration (latency covered by exp+PV issue).
    f32x4 outacc[2][4];
    #pragma unroll
    for (int rt = 0; rt < 2; rt++)
        #pragma unroll
        for (int dt = 0; dt < 4; dt++) outacc[rt][dt] = (f32x4){0.f, 0.f, 0.f, 0.f};
    float den[2] = {0.f, 0.f};

    bf16x8 bK2[2][2];
    {
        const unsigned short* sK = (const unsigned short*)smem;   // chunk 0
        #pragma unroll
        for (int nt = 0; nt < 2; nt++)
            #pragma unroll
            for (int kc = 0; kc < 2; kc++)
                bK2[nt][kc] = *(const bf16x8*)&sK[((nt * 2 + kc) << 9) + lane * 8];
    }
    f32x4 sv[2][2];                               // [nt][rt]
    #pragma unroll
    for (int nt = 0; nt < 2; nt++)
        #pragma unroll
        for (int rt = 0; rt < 2; rt++) {
            f32x4 z = {0.f, 0.f, 0.f, 0.f};
            z = __builtin_amdgcn_mfma_f32_16x16x32_bf16(bK2[nt][0], aQ[rt][0], z, 0, 0, 0);
            sv[nt][rt] = __builtin_amdgcn_mfma_f32_16x16x32_bf16(bK2[nt][1], aQ[rt][1], z, 0, 0, 0);
        }

    for (int cc = 0; cc < 16; cc++) {
        const unsigned short* sV = (const unsigned short*)(smem + cc * SLAB + 4096);
        bf16x8 bV[4];
        #pragma unroll
        for (int dt = 0; dt < 4; dt++)
            bV[dt] = *(const bf16x8*)&sV[dt * 512 + lane * 8];
        if (cc < 15) {                            // load next chunk's K frags
            const unsigned short* sKn = (const unsigned short*)(smem + (cc + 1) * SLAB);
            #pragma unroll
            for (int nt = 0; nt < 2; nt++)
                #pragma unroll
                for (int kc = 0; kc < 2; kc++)
                    bK2[nt][kc] = *(const bf16x8*)&sKn[((nt * 2 + kc) << 9) + lane * 8];
        }
        bf16x8 aP[2];
        #pragma unroll
        for (int rt = 0; rt < 2; rt++)
            #pragma unroll
            for (int nt = 0; nt < 2; nt++)
                #pragma unroll
                for (int reg = 0; reg < 4; reg++) {
                    float p = __builtin_amdgcn_exp2f(sv[nt][rt][reg]);
                    den[rt] += p;
                    aP[rt][nt * 4 + reg] = (__bf16)p;
                }
        __builtin_amdgcn_s_setprio(1);
        #pragma unroll
        for (int dt = 0; dt < 4; dt++) {
            outacc[0][dt] = __builtin_amdgcn_mfma_f32_16x16x32_bf16(aP[0], bV[dt], outacc[0][dt], 0, 0, 0);
            outacc[1][dt] = __builtin_amdgcn_mfma_f32_16x16x32_bf16(aP[1], bV[dt], outacc[1][dt], 0, 0, 0);
        }
        if (cc < 15) {
            #pragma unroll
            for (int nt = 0; nt < 2; nt++)
                #pragma unroll
                for (int rt = 0; rt < 2; rt++) {
                    f32x4 z = {0.f, 0.f, 0.f, 0.f};
                    z = __builtin_amdgcn_mfma_f32_16x16x32_bf16(bK2[nt][0], aQ[rt][0], z, 0, 0, 0);
                    sv[nt][rt] = __builtin_amdgcn_mfma_f32_16x16x32_bf16(bK2[nt][1], aQ[rt][1], z, 0, 0, 0);
                }
        }
        __builtin_amdgcn_s_setprio(0);
    }

    // ---- epilogue: den reduce (per q=lc, sum over quads), redistribute ---
    float rden[2][4];
    #pragma unroll
    for (int rt = 0; rt < 2; rt++) {
        float d2 = den[rt];
        d2 += __shfl_xor(d2, 16);
        d2 += __shfl_xor(d2, 32);
        d2 = 1.0f / d2;
        #pragma unroll
        for (int reg = 0; reg < 4; reg++)
            rden[rt][reg] = __shfl(d2, quad * 4 + reg);
    }
    #pragma unroll
    for (int dt = 0; dt < 4; dt++) {
        float ps = 0.f;
        #pragma unroll
        for (int rt = 0; rt < 2; rt++)
            #pragma unroll
            for (int reg = 0; reg < 4; reg++)
                ps += outacc[rt][dt][reg] * rden[rt][reg];
        ps += __shfl_xor(ps, 16);
        ps += __shfl_xor(ps, 32);
        if (quad == 0) redw[dt * 16 + lc] = ps;   // xstage region (dead)
    }
    __syncthreads();
    if (t < 64) {
        float s = 0.f;
        #pragma unroll
        for (int ww = 0; ww < 16; ww++)
            s += *(const float*)(smem + 16 * SLAB + ww * 256 + t * 4);
        pooled[t] = s * (1.0f / 512.0f);
    }
    __syncthreads();
    if (t < NCLASS) {
        float acc = fcb[t];
        #pragma unroll
        for (int d = 0; d < 64; d++) acc += pooled[d] * fcw[t * 64 + d];
        outp[b * NCLASS + t] = acc;
    }
}

// ---------------------------------------------------------------------------
extern "C" void kernel_launch(void* const* d_in, const int* in_sizes, int n_in,
                              void* d_out, int out_size, void* d_ws, size_t ws_size,
                              hipStream_t stream)
{
    const float* x   = (const float*)d_in[0];
    const float* w1  = (const float*)d_in[1];
    const float* cb1 = (const float*)d_in[2];
    const float* g1  = (const float*)d_in[3];
    const float* be1 = (const float*)d_in[4];
    const float* m1  = (const float*)d_in[5];
    const float* v1  = (const float*)d_in[6];
    const float* w2  = (const float*)d_in[7];
    const float* cb2 = (const float*)d_in[8];
    const float* g2  = (const float*)d_in[9];
    const float* be2 = (const float*)d_in[10];
    const float* m2  = (const float*)d_in[11];
    const float* v2  = (const float*)d_in[12];
    const float* wq  = (const float*)d_in[13];
    const float* bq  = (const float*)d_in[14];
    const float* wk  = (const float*)d_in[15];
    const float* bk  = (const float*)d_in[16];
    const float* wv  = (const float*)d_in[17];
    const float* bv  = (const float*)d_in[18];
    const float* fcw = (const float*)d_in[19];
    const float* fcb = (const float*)d_in[20];
    float* out = (float*)d_out;

    char* ws = (char*)d_ws;
    unsigned short* w1p = (unsigned short*)(ws);            // 2048 B
    float*          b1f = (float*)(ws + 2048u);             // 128 B
    float*          b2f = (float*)(ws + 2176u);             // 256 B
    unsigned short* w2p = (unsigned short*)(ws + 2432u);    // 12288 B
    unsigned short* wqp = (unsigned short*)(ws + 14720u);   // 8192 B
    unsigned short* wkp = (unsigned short*)(ws + 22912u);   // 8192 B
    unsigned short* wvp = (unsigned short*)(ws + 31104u);   // 8192 B

    prep_weights<<<dim3(1), 256, 0, stream>>>(w1, cb1, g1, be1, m1, v1,
                                              w2, cb2, g2, be2, m2, v2,
                                              wq, wk, wv,
                                              w1p, b1f, w2p, b2f, wqp, wkp, wvp);
    fused_all<<<dim3(NB), 1024, 0, stream>>>(x, w1p, b1f, w2p, b2f,
                                             wqp, wkp, wvp,
                                             bq, bk, bv, fcw, fcb, out);
}

// Round 3
// 124.175 us; speedup vs baseline: 1.0981x; 1.0469x over previous
//
#include <hip/hip_runtime.h>
#include <hip/hip_bf16.h>

// B=256, C_IN=6, L=512, C1=32, C2=D=64, NCLASS=10.
// Megakernel v12: v11 + 8-wave blocks (512 thr), each wave owns 64 queries
// (two 32-position groups, sg-loop over the v11 per-wave conv pipeline).
// Rationale: attention's DS traffic is (waves) x 128KB of K/V streaming; the
// DS pipe (~12cy per ds_read_b128, CU-shared) was the measured wall. Halving
// the wave count halves per-CU attn DS cycles while keeping total MFMA/VALU
// per SIMD constant (2 waves x 2x work). VGPR ~190 fits 2 waves/SIMD.
// prep_weights parallelized across 8 blocks.
// LDS 139264 B (16 x 8192 slab + 8192 xstage). ws: prepped weights only.

#define NB 256
#define LL 512
#define CIN 6
#define NCLASS 10
#define SLAB 8192
#define QSC 0.18033688f   // 0.125 * log2(e): exp(s/8) == exp2(s*QSC)

typedef __bf16 bf16x8 __attribute__((ext_vector_type(8)));
typedef float f32x4 __attribute__((ext_vector_type(4)));
typedef unsigned short us4 __attribute__((ext_vector_type(4)));
typedef unsigned short us8 __attribute__((ext_vector_type(8)));
typedef unsigned int u32x4 __attribute__((ext_vector_type(4)));

static __device__ __forceinline__ unsigned short f2b(float f) {
    __bf16 h = (__bf16)f;                       // RNE f32->bf16
    return __builtin_bit_cast(unsigned short, h);
}

// ---------------------------------------------------------------------------
// Kernel P: 8-block weight fold (<1 us of compute).
// w1p[c][k'=dl*8+ci] = w1[c][ci*3+dl]*inv1 (zeros at ci>=6 or dl==3).
// w2p[c2][k'=dl*32+ci]*inv2; b1f/b2f folded.
// wqp/wkp/wvp laid out with sigma_h on the channel (contraction) dim:
//   slot k' (kc=k'>>5, quad=(k'>>3)&3, e=k'&7) <- ch = kc*32+(e>>2)*16+quad*4+(e&3)
// ---------------------------------------------------------------------------
__global__ __launch_bounds__(256) void prep_weights(
    const float* __restrict__ w1, const float* __restrict__ cb1,
    const float* __restrict__ g1, const float* __restrict__ be1,
    const float* __restrict__ m1, const float* __restrict__ v1,
    const float* __restrict__ w2, const float* __restrict__ cb2,
    const float* __restrict__ g2, const float* __restrict__ be2,
    const float* __restrict__ m2, const float* __restrict__ v2,
    const float* __restrict__ wq, const float* __restrict__ wk,
    const float* __restrict__ wv,
    unsigned short* __restrict__ w1p, float* __restrict__ b1f,
    unsigned short* __restrict__ w2p, float* __restrict__ b2f,
    unsigned short* __restrict__ wqp, unsigned short* __restrict__ wkp,
    unsigned short* __restrict__ wvp)
{
    const int tt = blockIdx.x * 256 + threadIdx.x;    // 0..2047
    for (int idx = tt; idx < 1024; idx += 2048) {     // w1p [32][32], k'=dl*8+ci
        int c = idx >> 5, k = idx & 31;
        int dl = k >> 3, ci = k & 7;
        float inv = g1[c] * rsqrtf(v1[c] + 1e-5f);
        float val = (dl < 3 && ci < 6) ? w1[c * 18 + ci * 3 + dl] * inv : 0.f;
        w1p[idx] = f2b(val);
    }
    if (tt < 32) {
        float inv = g1[tt] * rsqrtf(v1[tt] + 1e-5f);
        b1f[tt] = be1[tt] + (cb1[tt] - m1[tt]) * inv;
    }
    for (int idx = tt; idx < 2048; idx += 2048) {     // w2p [64][96], k'=dl*32+ci
        int c2 = idx >> 5, ci = idx & 31;
        float inv = g2[c2] * rsqrtf(v2[c2] + 1e-5f);
        const float* wp = w2 + c2 * 96 + ci * 3;
        w2p[c2 * 96 +      ci] = f2b(wp[0] * inv);
        w2p[c2 * 96 + 32 + ci] = f2b(wp[1] * inv);
        w2p[c2 * 96 + 64 + ci] = f2b(wp[2] * inv);
    }
    if (tt >= 64 && tt < 128) {
        int c2 = tt - 64;
        float inv = g2[c2] * rsqrtf(v2[c2] + 1e-5f);
        b2f[c2] = be2[c2] + (cb2[c2] - m2[c2]) * inv;
    }
    for (int idx = tt; idx < 4096; idx += 2048) {     // sigma_h permuted
        int d = idx >> 6, k = idx & 63;
        int kc = k >> 5, quad = (k >> 3) & 3, e = k & 7;
        int ch = kc * 32 + (e >> 2) * 16 + quad * 4 + (e & 3);
        wqp[idx] = f2b(wq[d * 64 + ch] * QSC);        // fold 1/8 * log2e
        wkp[idx] = f2b(wk[d * 64 + ch]);
        wvp[idx] = f2b(wv[d * 64 + ch]);
    }
}

// ---------------------------------------------------------------------------
// Megakernel v12. LDS: 16 slabs x 8192 B + xstage 8192 B = 139264 B.
// Slab g (g=2w+sg): conv: h1sl[34][40] @0 (dead before Kf written)
//                   attn: Kf @0 (4096) | Vf @4096 (4096, key-perm, frag order)
// xstage [512][8] u16 (dead after P1); epilogue redw/pooled in xstage region.
// ---------------------------------------------------------------------------
__global__ __launch_bounds__(512, 2) void fused_all(
    const float* __restrict__ x,
    const unsigned short* __restrict__ w1p, const float* __restrict__ b1f,
    const unsigned short* __restrict__ w2p, const float* __restrict__ b2f,
    const unsigned short* __restrict__ wqp, const unsigned short* __restrict__ wkp,
    const unsigned short* __restrict__ wvp,
    const float* __restrict__ bq, const float* __restrict__ bk,
    const float* __restrict__ bvp,
    const float* __restrict__ fcw, const float* __restrict__ fcb,
    float* __restrict__ outp)
{
    const int b = blockIdx.x;
    const int t = threadIdx.x;
    const int w = t >> 6, lane = t & 63, quad = lane >> 4, lc = lane & 15;

    __shared__ __align__(16) char smem[16 * SLAB + 8192];   // 139264 B
    unsigned short* xstage = (unsigned short*)(smem + 16 * SLAB);  // [512][8]
    float* redw   = (float*)(smem + 16 * SLAB) + w * 64;     // epilogue (xstage dead)
    float* pooled = (float*)(smem + 16 * SLAB + 4096);

    // ---- P0: stage x[b] transposed to [pos][ch(8)] bf16 (b128 rows) ------
    {
        us8 pk;
        #pragma unroll
        for (int ci = 0; ci < 6; ci++)
            pk[ci] = f2b(x[((size_t)b * CIN + ci) * LL + t]);  // coalesced per ci
        pk[6] = 0; pk[7] = 0;
        *(us8*)&xstage[t * 8] = pk;
    }
    __syncthreads();

    // ---- conv + qkv pipeline, twice per wave (groups g = 2w, 2w+1) -------
    bf16x8 aQ4[4][2];                 // rt4 = sg*2 + rt
    #pragma unroll
    for (int sg = 0; sg < 2; sg++) {
        const int g = 2 * w + sg;
        char* gslab = smem + g * SLAB;
        unsigned short* h1sl = (unsigned short*)gslab;          // conv scratch
        unsigned short* Kf   = (unsigned short*)gslab;          // attn frag order
        unsigned short* Vf   = (unsigned short*)(gslab + 4096);

        // ---- P1: conv1 swapped: h1 = mfma(W1, X) -------------------------
        bf16x8 bW1[2];
        #pragma unroll
        for (int nt = 0; nt < 2; nt++)
            bW1[nt] = *(const bf16x8*)(w1p + (nt * 16 + lc) * 32 + quad * 8);
        f32x4 b1q[2];
        #pragma unroll
        for (int nt = 0; nt < 2; nt++)
            b1q[nt] = *(const f32x4*)&b1f[nt * 16 + quad * 4];
        #pragma unroll
        for (int mt = 0; mt < 3; mt++) {
            int j = mt * 16 + lc;                 // 0..47, keep <34
            int P = g * 32 - 1 + j;               // output position (halo +-1)
            int src = P + quad - 1;               // x position for dl=quad
            bool okx = (src >= 0) && (src < LL);  // quad==3 -> weight is zero
            int srcc = src < 0 ? 0 : (src > 511 ? 511 : src);
            u32x4 xv = *(const u32x4*)&xstage[srcc * 8];
            if (!okx) { xv[0] = 0u; xv[1] = 0u; xv[2] = 0u; xv[3] = 0u; }
            bf16x8 aX = __builtin_bit_cast(bf16x8, xv);
            bool pv = (P >= 0) && (P < LL);
            #pragma unroll
            for (int nt = 0; nt < 2; nt++) {
                f32x4 z = {0.f, 0.f, 0.f, 0.f};
                f32x4 h = __builtin_amdgcn_mfma_f32_16x16x32_bf16(bW1[nt], aX, z, 0, 0, 0);
                us4 pk;
                #pragma unroll
                for (int r = 0; r < 4; r++) {
                    float y = h[r] + b1q[nt][r];
                    y = (pv && y > 0.f) ? y : 0.f;
                    pk[r] = f2b(y);
                }
                if (j < 34)
                    *(us4*)&h1sl[j * 40 + nt * 16 + quad * 4] = pk;
            }
        }

        // ---- P2: conv2 as GEMM (M=64 c2, N=32 rows, K=96) ----------------
        bf16x8 bX[2][3], aW2[4][3];
        #pragma unroll
        for (int rt = 0; rt < 2; rt++)
            #pragma unroll
            for (int kc = 0; kc < 3; kc++)
                bX[rt][kc] = *(const bf16x8*)&h1sl[(rt * 16 + lc + kc) * 40 + quad * 8];
        #pragma unroll
        for (int nt = 0; nt < 4; nt++)
            #pragma unroll
            for (int kc = 0; kc < 3; kc++)
                aW2[nt][kc] = *(const bf16x8*)(w2p + (nt * 16 + lc) * 96 + kc * 32 + quad * 8);

        f32x4 acc2[4][2];
        #pragma unroll
        for (int nt = 0; nt < 4; nt++)
            #pragma unroll
            for (int rt = 0; rt < 2; rt++) {
                f32x4 a = {0.f, 0.f, 0.f, 0.f};
                a = __builtin_amdgcn_mfma_f32_16x16x32_bf16(aW2[nt][0], bX[rt][0], a, 0, 0, 0);
                a = __builtin_amdgcn_mfma_f32_16x16x32_bf16(aW2[nt][1], bX[rt][1], a, 0, 0, 0);
                acc2[nt][rt] = __builtin_amdgcn_mfma_f32_16x16x32_bf16(aW2[nt][2], bX[rt][2], a, 0, 0, 0);
            }

        // ---- P3a: +b2f, relu -> aH in REGISTERS (sigma_h frag order) -----
        bf16x8 aH[2][2];
        #pragma unroll
        for (int nt2 = 0; nt2 < 4; nt2++) {
            f32x4 bb2 = *(const f32x4*)&b2f[nt2 * 16 + quad * 4];
            #pragma unroll
            for (int rt = 0; rt < 2; rt++)
                #pragma unroll
                for (int reg = 0; reg < 4; reg++) {
                    float y = acc2[nt2][rt][reg] + bb2[reg];
                    aH[rt][nt2 >> 1][(nt2 & 1) * 4 + reg] = (__bf16)(y > 0.f ? y : 0.f);
                }
        }

        // ---- P3b: q in registers (sigma_d); k -> Kf as 4 x b128 ----------
        {
            f32x4 Cq[4][2], bbq[4];
            #pragma unroll
            for (int nt = 0; nt < 4; nt++) {
                bf16x8 aW0 = *(const bf16x8*)(wqp + (nt * 16 + lc) * 64 + quad * 8);
                bf16x8 aW1 = *(const bf16x8*)(wqp + (nt * 16 + lc) * 64 + 32 + quad * 8);
                bbq[nt] = *(const f32x4*)&bq[nt * 16 + quad * 4];
                #pragma unroll
                for (int rt = 0; rt < 2; rt++) {
                    f32x4 a = {0.f, 0.f, 0.f, 0.f};
                    a = __builtin_amdgcn_mfma_f32_16x16x32_bf16(aW0, aH[rt][0], a, 0, 0, 0);
                    Cq[nt][rt] = __builtin_amdgcn_mfma_f32_16x16x32_bf16(aW1, aH[rt][1], a, 0, 0, 0);
                }
            }
            #pragma unroll
            for (int rt = 0; rt < 2; rt++)
                #pragma unroll
                for (int nt = 0; nt < 4; nt++)
                    #pragma unroll
                    for (int reg = 0; reg < 4; reg++)
                        aQ4[sg * 2 + rt][nt >> 1][(nt & 1) * 4 + reg] =
                            (__bf16)(Cq[nt][rt][reg] + bbq[nt][reg] * QSC);
        }
        {
            f32x4 Ck[4][2], bbk[4];
            #pragma unroll
            for (int nt = 0; nt < 4; nt++) {
                bf16x8 aW0 = *(const bf16x8*)(wkp + (nt * 16 + lc) * 64 + quad * 8);
                bf16x8 aW1 = *(const bf16x8*)(wkp + (nt * 16 + lc) * 64 + 32 + quad * 8);
                bbk[nt] = *(const f32x4*)&bk[nt * 16 + quad * 4];
                #pragma unroll
                for (int rt = 0; rt < 2; rt++) {
                    f32x4 a = {0.f, 0.f, 0.f, 0.f};
                    a = __builtin_amdgcn_mfma_f32_16x16x32_bf16(aW0, aH[rt][0], a, 0, 0, 0);
                    Ck[nt][rt] = __builtin_amdgcn_mfma_f32_16x16x32_bf16(aW1, aH[rt][1], a, 0, 0, 0);
                }
            }
            #pragma unroll
            for (int rt = 0; rt < 2; rt++)
                #pragma unroll
                for (int kc = 0; kc < 2; kc++) {
                    us8 pk;
                    #pragma unroll
                    for (int e = 0; e < 8; e++) {
                        int nt = kc * 2 + (e >> 2), reg = e & 3;
                        pk[e] = f2b(Ck[nt][rt][reg] + bbk[nt][reg]);
                    }
                    *(us8*)&Kf[((rt * 2 + kc) << 9) + lane * 8] = pk;
                }
        }

        // ---- P3c: v -> Vf as 4 x b128 (key-permuted frag order) ----------
        #pragma unroll
        for (int nt = 0; nt < 4; nt++) {
            bf16x8 bW0 = *(const bf16x8*)(wvp + (nt * 16 + lc) * 64 + quad * 8);
            bf16x8 bW1 = *(const bf16x8*)(wvp + (nt * 16 + lc) * 64 + 32 + quad * 8);
            const float bvv = bvp[nt * 16 + lc];
            f32x4 a0, a1;
            {
                f32x4 z = {0.f, 0.f, 0.f, 0.f};
                z = __builtin_amdgcn_mfma_f32_16x16x32_bf16(aH[0][0], bW0, z, 0, 0, 0);
                a0 = __builtin_amdgcn_mfma_f32_16x16x32_bf16(aH[0][1], bW1, z, 0, 0, 0);
            }
            {
                f32x4 z = {0.f, 0.f, 0.f, 0.f};
                z = __builtin_amdgcn_mfma_f32_16x16x32_bf16(aH[1][0], bW0, z, 0, 0, 0);
                a1 = __builtin_amdgcn_mfma_f32_16x16x32_bf16(aH[1][1], bW1, z, 0, 0, 0);
            }
            us8 pk;
            #pragma unroll
            for (int reg = 0; reg < 4; reg++) {
                pk[reg]     = f2b(a0[reg] + bvv);
                pk[4 + reg] = f2b(a1[reg] + bvv);
            }
            *(us8*)&Vf[nt * 512 + lane * 8] = pk;
        }
    }

    __syncthreads();          // all waves' Kf/Vf ready — only pre-attn barrier

    // ---- attention: 16 chunks, 64 q/wave, in-reg softmax, pipelined ------
    // sv[nt][rt4] holds QK(cc) computed at END of iter cc-1 (or prologue).
    f32x4 outacc[4][4];
    #pragma unroll
    for (int rt = 0; rt < 4; rt++)
        #pragma unroll
        for (int dt = 0; dt < 4; dt++) outacc[rt][dt] = (f32x4){0.f, 0.f, 0.f, 0.f};
    float den[4] = {0.f, 0.f, 0.f, 0.f};

    bf16x8 bK2[2][2];
    {
        const unsigned short* sK = (const unsigned short*)smem;   // chunk 0
        #pragma unroll
        for (int nt = 0; nt < 2; nt++)
            #pragma unroll
            for (int kc = 0; kc < 2; kc++)
                bK2[nt][kc] = *(const bf16x8*)&sK[((nt * 2 + kc) << 9) + lane * 8];
    }
    f32x4 sv[2][4];                               // [nt][rt4]
    #pragma unroll
    for (int nt = 0; nt < 2; nt++)
        #pragma unroll
        for (int rt = 0; rt < 4; rt++) {
            f32x4 z = {0.f, 0.f, 0.f, 0.f};
            z = __builtin_amdgcn_mfma_f32_16x16x32_bf16(bK2[nt][0], aQ4[rt][0], z, 0, 0, 0);
            sv[nt][rt] = __builtin_amdgcn_mfma_f32_16x16x32_bf16(bK2[nt][1], aQ4[rt][1], z, 0, 0, 0);
        }

    for (int cc = 0; cc < 16; cc++) {
        const unsigned short* sV = (const unsigned short*)(smem + cc * SLAB + 4096);
        bf16x8 bV[4];
        #pragma unroll
        for (int dt = 0; dt < 4; dt++)
            bV[dt] = *(const bf16x8*)&sV[dt * 512 + lane * 8];
        if (cc < 15) {                            // load next chunk's K frags
            const unsigned short* sKn = (const unsigned short*)(smem + (cc + 1) * SLAB);
            #pragma unroll
            for (int nt = 0; nt < 2; nt++)
                #pragma unroll
                for (int kc = 0; kc < 2; kc++)
                    bK2[nt][kc] = *(const bf16x8*)&sKn[((nt * 2 + kc) << 9) + lane * 8];
        }
        bf16x8 aP[4];
        #pragma unroll
        for (int rt = 0; rt < 4; rt++)
            #pragma unroll
            for (int nt = 0; nt < 2; nt++)
                #pragma unroll
                for (int reg = 0; reg < 4; reg++) {
                    float p = __builtin_amdgcn_exp2f(sv[nt][rt][reg]);
                    den[rt] += p;
                    aP[rt][nt * 4 + reg] = (__bf16)p;
                }
        __builtin_amdgcn_s_setprio(1);
        #pragma unroll
        for (int rt = 0; rt < 4; rt++)
            #pragma unroll
            for (int dt = 0; dt < 4; dt++)
                outacc[rt][dt] = __builtin_amdgcn_mfma_f32_16x16x32_bf16(aP[rt], bV[dt], outacc[rt][dt], 0, 0, 0);
        if (cc < 15) {
            #pragma unroll
            for (int nt = 0; nt < 2; nt++)
                #pragma unroll
                for (int rt = 0; rt < 4; rt++) {
                    f32x4 z = {0.f, 0.f, 0.f, 0.f};
                    z = __builtin_amdgcn_mfma_f32_16x16x32_bf16(bK2[nt][0], aQ4[rt][0], z, 0, 0, 0);
                    sv[nt][rt] = __builtin_amdgcn_mfma_f32_16x16x32_bf16(bK2[nt][1], aQ4[rt][1], z, 0, 0, 0);
                }
        }
        __builtin_amdgcn_s_setprio(0);
    }

    // ---- epilogue: den reduce (per q=lc, sum over quads), redistribute ---
    float rden[4][4];
    #pragma unroll
    for (int rt = 0; rt < 4; rt++) {
        float d2 = den[rt];
        d2 += __shfl_xor(d2, 16);
        d2 += __shfl_xor(d2, 32);
        d2 = 1.0f / d2;
        #pragma unroll
        for (int reg = 0; reg < 4; reg++)
            rden[rt][reg] = __shfl(d2, quad * 4 + reg);
    }
    #pragma unroll
    for (int dt = 0; dt < 4; dt++) {
        float ps = 0.f;
        #pragma unroll
        for (int rt = 0; rt < 4; rt++)
            #pragma unroll
            for (int reg = 0; reg < 4; reg++)
                ps += outacc[rt][dt][reg] * rden[rt][reg];
        ps += __shfl_xor(ps, 16);
        ps += __shfl_xor(ps, 32);
        if (quad == 0) redw[dt * 16 + lc] = ps;   // xstage region (dead)
    }
    __syncthreads();
    if (t < 64) {
        float s = 0.f;
        #pragma unroll
        for (int ww = 0; ww < 8; ww++)
            s += *(const float*)(smem + 16 * SLAB + ww * 256 + t * 4);
        pooled[t] = s * (1.0f / 512.0f);
    }
    __syncthreads();
    if (t < NCLASS) {
        float acc = fcb[t];
        #pragma unroll
        for (int d = 0; d < 64; d++) acc += pooled[d] * fcw[t * 64 + d];
        outp[b * NCLASS + t] = acc;
    }
}

// ---------------------------------------------------------------------------
extern "C" void kernel_launch(void* const* d_in, const int* in_sizes, int n_in,
                              void* d_out, int out_size, void* d_ws, size_t ws_size,
                              hipStream_t stream)
{
    const float* x   = (const float*)d_in[0];
    const float* w1  = (const float*)d_in[1];
    const float* cb1 = (const float*)d_in[2];
    const float* g1  = (const float*)d_in[3];
    const float* be1 = (const float*)d_in[4];
    const float* m1  = (const float*)d_in[5];
    const float* v1  = (const float*)d_in[6];
    const float* w2  = (const float*)d_in[7];
    const float* cb2 = (const float*)d_in[8];
    const float* g2  = (const float*)d_in[9];
    const float* be2 = (const float*)d_in[10];
    const float* m2  = (const float*)d_in[11];
    const float* v2  = (const float*)d_in[12];
    const float* wq  = (const float*)d_in[13];
    const float* bq  = (const float*)d_in[14];
    const float* wk  = (const float*)d_in[15];
    const float* bk  = (const float*)d_in[16];
    const float* wv  = (const float*)d_in[17];
    const float* bv  = (const float*)d_in[18];
    const float* fcw = (const float*)d_in[19];
    const float* fcb = (const float*)d_in[20];
    float* out = (float*)d_out;

    char* ws = (char*)d_ws;
    unsigned short* w1p = (unsigned short*)(ws);            // 2048 B
    float*          b1f = (float*)(ws + 2048u);             // 128 B
    float*          b2f = (float*)(ws + 2176u);             // 256 B
    unsigned short* w2p = (unsigned short*)(ws + 2432u);    // 12288 B
    unsigned short* wqp = (unsigned short*)(ws + 14720u);   // 8192 B
    unsigned short* wkp = (unsigned short*)(ws + 22912u);   // 8192 B
    unsigned short* wvp = (unsigned short*)(ws + 31104u);   // 8192 B

    prep_weights<<<dim3(8), 256, 0, stream>>>(w1, cb1, g1, be1, m1, v1,
                                              w2, cb2, g2, be2, m2, v2,
                                              wq, wk, wv,
                                              w1p, b1f, w2p, b2f, wqp, wkp, wvp);
    fused_all<<<dim3(NB), 512, 0, stream>>>(x, w1p, b1f, w2p, b2f,
                                            wqp, wkp, wvp,
                                            bq, bk, bv, fcw, fcb, out);
}

// Round 4
// 119.889 us; speedup vs baseline: 1.1374x; 1.0358x over previous
//
#include <hip/hip_runtime.h>
#include <hip/hip_bf16.h>

// B=256, C_IN=6, L=512, C1=32, C2=D=64, NCLASS=10.
// Megakernel v13: v12 + (a) sg-inner conv restructure: every weight fragment
// (w1p/w2p/wqp/wkp/wvp) is loaded ONCE per wave and feeds 4 independent
// MFMA chains (sg x rt) -> half the global-load latency chains, 2x ILP each;
// (b) denominator via ones-column MFMA: accDen[rt] = mfma(aP[rt], 1s, accDen)
// replaces 32 VALU adds/chunk/wave and the epilogue's cross-lane den reduce
// (accDen[rt][reg] holds the full den for q=quad*4+reg, replicated over lc).
// LDS 139264 B (16 x 8192 slab + 8192 xstage). ws: prepped weights only.

#define NB 256
#define LL 512
#define CIN 6
#define NCLASS 10
#define SLAB 8192
#define QSC 0.18033688f   // 0.125 * log2(e): exp(s/8) == exp2(s*QSC)

typedef __bf16 bf16x8 __attribute__((ext_vector_type(8)));
typedef float f32x4 __attribute__((ext_vector_type(4)));
typedef unsigned short us4 __attribute__((ext_vector_type(4)));
typedef unsigned short us8 __attribute__((ext_vector_type(8)));
typedef unsigned int u32x4 __attribute__((ext_vector_type(4)));

static __device__ __forceinline__ unsigned short f2b(float f) {
    __bf16 h = (__bf16)f;                       // RNE f32->bf16
    return __builtin_bit_cast(unsigned short, h);
}

// ---------------------------------------------------------------------------
// Kernel P: 8-block weight fold (<1 us of compute).
// w1p[c][k'=dl*8+ci] = w1[c][ci*3+dl]*inv1 (zeros at ci>=6 or dl==3).
// w2p[c2][k'=dl*32+ci]*inv2; b1f/b2f folded.
// wqp/wkp/wvp laid out with sigma_h on the channel (contraction) dim:
//   slot k' (kc=k'>>5, quad=(k'>>3)&3, e=k'&7) <- ch = kc*32+(e>>2)*16+quad*4+(e&3)
// ---------------------------------------------------------------------------
__global__ __launch_bounds__(256) void prep_weights(
    const float* __restrict__ w1, const float* __restrict__ cb1,
    const float* __restrict__ g1, const float* __restrict__ be1,
    const float* __restrict__ m1, const float* __restrict__ v1,
    const float* __restrict__ w2, const float* __restrict__ cb2,
    const float* __restrict__ g2, const float* __restrict__ be2,
    const float* __restrict__ m2, const float* __restrict__ v2,
    const float* __restrict__ wq, const float* __restrict__ wk,
    const float* __restrict__ wv,
    unsigned short* __restrict__ w1p, float* __restrict__ b1f,
    unsigned short* __restrict__ w2p, float* __restrict__ b2f,
    unsigned short* __restrict__ wqp, unsigned short* __restrict__ wkp,
    unsigned short* __restrict__ wvp)
{
    const int tt = blockIdx.x * 256 + threadIdx.x;    // 0..2047
    for (int idx = tt; idx < 1024; idx += 2048) {     // w1p [32][32], k'=dl*8+ci
        int c = idx >> 5, k = idx & 31;
        int dl = k >> 3, ci = k & 7;
        float inv = g1[c] * rsqrtf(v1[c] + 1e-5f);
        float val = (dl < 3 && ci < 6) ? w1[c * 18 + ci * 3 + dl] * inv : 0.f;
        w1p[idx] = f2b(val);
    }
    if (tt < 32) {
        float inv = g1[tt] * rsqrtf(v1[tt] + 1e-5f);
        b1f[tt] = be1[tt] + (cb1[tt] - m1[tt]) * inv;
    }
    for (int idx = tt; idx < 2048; idx += 2048) {     // w2p [64][96], k'=dl*32+ci
        int c2 = idx >> 5, ci = idx & 31;
        float inv = g2[c2] * rsqrtf(v2[c2] + 1e-5f);
        const float* wp = w2 + c2 * 96 + ci * 3;
        w2p[c2 * 96 +      ci] = f2b(wp[0] * inv);
        w2p[c2 * 96 + 32 + ci] = f2b(wp[1] * inv);
        w2p[c2 * 96 + 64 + ci] = f2b(wp[2] * inv);
    }
    if (tt >= 64 && tt < 128) {
        int c2 = tt - 64;
        float inv = g2[c2] * rsqrtf(v2[c2] + 1e-5f);
        b2f[c2] = be2[c2] + (cb2[c2] - m2[c2]) * inv;
    }
    for (int idx = tt; idx < 4096; idx += 2048) {     // sigma_h permuted
        int d = idx >> 6, k = idx & 63;
        int kc = k >> 5, quad = (k >> 3) & 3, e = k & 7;
        int ch = kc * 32 + (e >> 2) * 16 + quad * 4 + (e & 3);
        wqp[idx] = f2b(wq[d * 64 + ch] * QSC);        // fold 1/8 * log2e
        wkp[idx] = f2b(wk[d * 64 + ch]);
        wvp[idx] = f2b(wv[d * 64 + ch]);
    }
}

// ---------------------------------------------------------------------------
// Megakernel v13. LDS: 16 slabs x 8192 B + xstage 8192 B = 139264 B.
// Slab g (g=2w+sg): conv: h1sl[34][40] @0 (dead before Kf written)
//                   attn: Kf @0 (4096) | Vf @4096 (4096, key-perm, frag order)
// xstage [512][8] u16 (dead after P1); epilogue redw/pooled in xstage region.
// ---------------------------------------------------------------------------
__global__ __launch_bounds__(512, 2) void fused_all(
    const float* __restrict__ x,
    const unsigned short* __restrict__ w1p, const float* __restrict__ b1f,
    const unsigned short* __restrict__ w2p, const float* __restrict__ b2f,
    const unsigned short* __restrict__ wqp, const unsigned short* __restrict__ wkp,
    const unsigned short* __restrict__ wvp,
    const float* __restrict__ bq, const float* __restrict__ bk,
    const float* __restrict__ bvp,
    const float* __restrict__ fcw, const float* __restrict__ fcb,
    float* __restrict__ outp)
{
    const int b = blockIdx.x;
    const int t = threadIdx.x;
    const int w = t >> 6, lane = t & 63, quad = lane >> 4, lc = lane & 15;

    __shared__ __align__(16) char smem[16 * SLAB + 8192];   // 139264 B
    unsigned short* xstage = (unsigned short*)(smem + 16 * SLAB);  // [512][8]
    float* redw   = (float*)(smem + 16 * SLAB) + w * 64;     // epilogue (xstage dead)
    float* pooled = (float*)(smem + 16 * SLAB + 4096);

    unsigned short* slab[2] = { (unsigned short*)(smem + (2 * w) * SLAB),
                                (unsigned short*)(smem + (2 * w + 1) * SLAB) };

    // ---- P0: stage x[b] transposed to [pos][ch(8)] bf16 (b128 rows) ------
    {
        us8 pk;
        #pragma unroll
        for (int ci = 0; ci < 6; ci++)
            pk[ci] = f2b(x[((size_t)b * CIN + ci) * LL + t]);  // coalesced per ci
        pk[6] = 0; pk[7] = 0;
        *(us8*)&xstage[t * 8] = pk;
    }
    __syncthreads();

    // ---- P1: conv1 swapped: h1 = mfma(W1, X), both groups ----------------
    {
        bf16x8 bW1[2];
        #pragma unroll
        for (int nt = 0; nt < 2; nt++)
            bW1[nt] = *(const bf16x8*)(w1p + (nt * 16 + lc) * 32 + quad * 8);
        f32x4 b1q[2];
        #pragma unroll
        for (int nt = 0; nt < 2; nt++)
            b1q[nt] = *(const f32x4*)&b1f[nt * 16 + quad * 4];
        #pragma unroll
        for (int sg = 0; sg < 2; sg++) {
            const int g = 2 * w + sg;
            unsigned short* h1sl = slab[sg];
            #pragma unroll
            for (int mt = 0; mt < 3; mt++) {
                int j = mt * 16 + lc;                 // 0..47, keep <34
                int P = g * 32 - 1 + j;               // output position (halo +-1)
                int src = P + quad - 1;               // x position for dl=quad
                bool okx = (src >= 0) && (src < LL);  // quad==3 -> weight is zero
                int srcc = src < 0 ? 0 : (src > 511 ? 511 : src);
                u32x4 xv = *(const u32x4*)&xstage[srcc * 8];
                if (!okx) { xv[0] = 0u; xv[1] = 0u; xv[2] = 0u; xv[3] = 0u; }
                bf16x8 aX = __builtin_bit_cast(bf16x8, xv);
                bool pv = (P >= 0) && (P < LL);
                #pragma unroll
                for (int nt = 0; nt < 2; nt++) {
                    f32x4 z = {0.f, 0.f, 0.f, 0.f};
                    f32x4 h = __builtin_amdgcn_mfma_f32_16x16x32_bf16(bW1[nt], aX, z, 0, 0, 0);
                    us4 pk;
                    #pragma unroll
                    for (int r = 0; r < 4; r++) {
                        float y = h[r] + b1q[nt][r];
                        y = (pv && y > 0.f) ? y : 0.f;
                        pk[r] = f2b(y);
                    }
                    if (j < 34)
                        *(us4*)&h1sl[j * 40 + nt * 16 + quad * 4] = pk;
                }
            }
        }
    }

    // ---- P2: conv2 as GEMM; weights loaded once, sg x rt chains ----------
    bf16x8 bX[2][2][3];                   // [sg][rt][kc]
    #pragma unroll
    for (int sg = 0; sg < 2; sg++)
        #pragma unroll
        for (int rt = 0; rt < 2; rt++)
            #pragma unroll
            for (int kc = 0; kc < 3; kc++)
                bX[sg][rt][kc] = *(const bf16x8*)&slab[sg][(rt * 16 + lc + kc) * 40 + quad * 8];

    f32x4 acc2[2][4][2];                  // [sg][nt][rt]
    #pragma unroll
    for (int nt = 0; nt < 4; nt++) {
        bf16x8 aW0 = *(const bf16x8*)(w2p + (nt * 16 + lc) * 96 + quad * 8);
        bf16x8 aW1 = *(const bf16x8*)(w2p + (nt * 16 + lc) * 96 + 32 + quad * 8);
        bf16x8 aW2 = *(const bf16x8*)(w2p + (nt * 16 + lc) * 96 + 64 + quad * 8);
        #pragma unroll
        for (int sg = 0; sg < 2; sg++)
            #pragma unroll
            for (int rt = 0; rt < 2; rt++) {
                f32x4 a = {0.f, 0.f, 0.f, 0.f};
                a = __builtin_amdgcn_mfma_f32_16x16x32_bf16(aW0, bX[sg][rt][0], a, 0, 0, 0);
                a = __builtin_amdgcn_mfma_f32_16x16x32_bf16(aW1, bX[sg][rt][1], a, 0, 0, 0);
                acc2[sg][nt][rt] = __builtin_amdgcn_mfma_f32_16x16x32_bf16(aW2, bX[sg][rt][2], a, 0, 0, 0);
            }
    }

    // ---- P3a: +b2f, relu -> aH in REGISTERS (sigma_h frag order) ---------
    bf16x8 aH[2][2][2];                   // [sg][rt][kc]
    #pragma unroll
    for (int nt2 = 0; nt2 < 4; nt2++) {
        f32x4 bb2 = *(const f32x4*)&b2f[nt2 * 16 + quad * 4];
        #pragma unroll
        for (int sg = 0; sg < 2; sg++)
            #pragma unroll
            for (int rt = 0; rt < 2; rt++)
                #pragma unroll
                for (int reg = 0; reg < 4; reg++) {
                    float y = acc2[sg][nt2][rt][reg] + bb2[reg];
                    aH[sg][rt][nt2 >> 1][(nt2 & 1) * 4 + reg] = (__bf16)(y > 0.f ? y : 0.f);
                }
    }

    // ---- biases for q/k (hoisted) ----------------------------------------
    f32x4 bbq[4], bbk[4];
    #pragma unroll
    for (int nt = 0; nt < 4; nt++) {
        bbq[nt] = *(const f32x4*)&bq[nt * 16 + quad * 4];
        bbk[nt] = *(const f32x4*)&bk[nt * 16 + quad * 4];
    }

    // ---- P3b-q: q fully in registers (sigma_d frag order), per-nt --------
    bf16x8 aQ4[4][2];                     // [rt4 = sg*2+rt][kc]
    #pragma unroll
    for (int nt = 0; nt < 4; nt++) {
        bf16x8 aW0 = *(const bf16x8*)(wqp + (nt * 16 + lc) * 64 + quad * 8);
        bf16x8 aW1 = *(const bf16x8*)(wqp + (nt * 16 + lc) * 64 + 32 + quad * 8);
        #pragma unroll
        for (int sg = 0; sg < 2; sg++)
            #pragma unroll
            for (int rt = 0; rt < 2; rt++) {
                f32x4 a = {0.f, 0.f, 0.f, 0.f};
                a = __builtin_amdgcn_mfma_f32_16x16x32_bf16(aW0, aH[sg][rt][0], a, 0, 0, 0);
                a = __builtin_amdgcn_mfma_f32_16x16x32_bf16(aW1, aH[sg][rt][1], a, 0, 0, 0);
                #pragma unroll
                for (int reg = 0; reg < 4; reg++)
                    aQ4[sg * 2 + rt][nt >> 1][(nt & 1) * 4 + reg] =
                        (__bf16)(a[reg] + bbq[nt][reg] * QSC);
            }
    }

    // ---- P3b-k: k -> Kf as 4 x b128 (sigma_d order), per-kc --------------
    #pragma unroll
    for (int kc = 0; kc < 2; kc++) {
        f32x4 Ck[2][2][2];                // [j][sg][rt], nt = kc*2+j
        #pragma unroll
        for (int j = 0; j < 2; j++) {
            int nt = kc * 2 + j;
            bf16x8 aW0 = *(const bf16x8*)(wkp + (nt * 16 + lc) * 64 + quad * 8);
            bf16x8 aW1 = *(const bf16x8*)(wkp + (nt * 16 + lc) * 64 + 32 + quad * 8);
            #pragma unroll
            for (int sg = 0; sg < 2; sg++)
                #pragma unroll
                for (int rt = 0; rt < 2; rt++) {
                    f32x4 a = {0.f, 0.f, 0.f, 0.f};
                    a = __builtin_amdgcn_mfma_f32_16x16x32_bf16(aW0, aH[sg][rt][0], a, 0, 0, 0);
                    Ck[j][sg][rt] = __builtin_amdgcn_mfma_f32_16x16x32_bf16(aW1, aH[sg][rt][1], a, 0, 0, 0);
                }
        }
        #pragma unroll
        for (int sg = 0; sg < 2; sg++)
            #pragma unroll
            for (int rt = 0; rt < 2; rt++) {
                us8 pk;
                #pragma unroll
                for (int e = 0; e < 8; e++) {
                    int j = e >> 2, reg = e & 3, nt = kc * 2 + j;
                    pk[e] = f2b(Ck[j][sg][rt][reg] + bbk[nt][reg]);
                }
                *(us8*)&slab[sg][((rt * 2 + kc) << 9) + lane * 8] = pk;   // Kf
            }
    }

    // ---- P3c: v -> Vf as 4 x b128 (key-permuted frag order), per-nt ------
    #pragma unroll
    for (int nt = 0; nt < 4; nt++) {
        bf16x8 bW0 = *(const bf16x8*)(wvp + (nt * 16 + lc) * 64 + quad * 8);
        bf16x8 bW1 = *(const bf16x8*)(wvp + (nt * 16 + lc) * 64 + 32 + quad * 8);
        const float bvv = bvp[nt * 16 + lc];
        #pragma unroll
        for (int sg = 0; sg < 2; sg++) {
            f32x4 a0, a1;
            {
                f32x4 z = {0.f, 0.f, 0.f, 0.f};
                z = __builtin_amdgcn_mfma_f32_16x16x32_bf16(aH[sg][0][0], bW0, z, 0, 0, 0);
                a0 = __builtin_amdgcn_mfma_f32_16x16x32_bf16(aH[sg][0][1], bW1, z, 0, 0, 0);
            }
            {
                f32x4 z = {0.f, 0.f, 0.f, 0.f};
                z = __builtin_amdgcn_mfma_f32_16x16x32_bf16(aH[sg][1][0], bW0, z, 0, 0, 0);
                a1 = __builtin_amdgcn_mfma_f32_16x16x32_bf16(aH[sg][1][1], bW1, z, 0, 0, 0);
            }
            us8 pk;
            #pragma unroll
            for (int reg = 0; reg < 4; reg++) {
                pk[reg]     = f2b(a0[reg] + bvv);
                pk[4 + reg] = f2b(a1[reg] + bvv);
            }
            *(us8*)&slab[sg][2048 + nt * 512 + lane * 8] = pk;            // Vf
        }
    }

    __syncthreads();          // all waves' Kf/Vf ready — only pre-attn barrier

    // ---- attention: 16 chunks, 64 q/wave, in-reg softmax, pipelined ------
    // sv[nt][rt4] holds QK(cc) computed at END of iter cc-1 (or prologue).
    // Denominator via ones-column MFMA: accDen[rt][reg] accumulates the full
    // key-sum for q = rt*16 + quad*4 + reg (replicated across lc).
    f32x4 outacc[4][4];
    #pragma unroll
    for (int rt = 0; rt < 4; rt++)
        #pragma unroll
        for (int dt = 0; dt < 4; dt++) outacc[rt][dt] = (f32x4){0.f, 0.f, 0.f, 0.f};
    f32x4 accDen[4];
    #pragma unroll
    for (int rt = 0; rt < 4; rt++) accDen[rt] = (f32x4){0.f, 0.f, 0.f, 0.f};
    bf16x8 bOne;
    #pragma unroll
    for (int e = 0; e < 8; e++) bOne[e] = (__bf16)1.0f;

    bf16x8 bK2[2][2];
    {
        const unsigned short* sK = (const unsigned short*)smem;   // chunk 0
        #pragma unroll
        for (int nt = 0; nt < 2; nt++)
            #pragma unroll
            for (int kc = 0; kc < 2; kc++)
                bK2[nt][kc] = *(const bf16x8*)&sK[((nt * 2 + kc) << 9) + lane * 8];
    }
    f32x4 sv[2][4];                               // [nt][rt4]
    #pragma unroll
    for (int nt = 0; nt < 2; nt++)
        #pragma unroll
        for (int rt = 0; rt < 4; rt++) {
            f32x4 z = {0.f, 0.f, 0.f, 0.f};
            z = __builtin_amdgcn_mfma_f32_16x16x32_bf16(bK2[nt][0], aQ4[rt][0], z, 0, 0, 0);
            sv[nt][rt] = __builtin_amdgcn_mfma_f32_16x16x32_bf16(bK2[nt][1], aQ4[rt][1], z, 0, 0, 0);
        }

    for (int cc = 0; cc < 16; cc++) {
        const unsigned short* sV = (const unsigned short*)(smem + cc * SLAB + 4096);
        bf16x8 bV[4];
        #pragma unroll
        for (int dt = 0; dt < 4; dt++)
            bV[dt] = *(const bf16x8*)&sV[dt * 512 + lane * 8];
        if (cc < 15) {                            // load next chunk's K frags
            const unsigned short* sKn = (const unsigned short*)(smem + (cc + 1) * SLAB);
            #pragma unroll
            for (int nt = 0; nt < 2; nt++)
                #pragma unroll
                for (int kc = 0; kc < 2; kc++)
                    bK2[nt][kc] = *(const bf16x8*)&sKn[((nt * 2 + kc) << 9) + lane * 8];
        }
        bf16x8 aP[4];
        #pragma unroll
        for (int rt = 0; rt < 4; rt++)
            #pragma unroll
            for (int nt = 0; nt < 2; nt++)
                #pragma unroll
                for (int reg = 0; reg < 4; reg++)
                    aP[rt][nt * 4 + reg] = (__bf16)__builtin_amdgcn_exp2f(sv[nt][rt][reg]);
        __builtin_amdgcn_s_setprio(1);
        #pragma unroll
        for (int rt = 0; rt < 4; rt++) {
            #pragma unroll
            for (int dt = 0; dt < 4; dt++)
                outacc[rt][dt] = __builtin_amdgcn_mfma_f32_16x16x32_bf16(aP[rt], bV[dt], outacc[rt][dt], 0, 0, 0);
            accDen[rt] = __builtin_amdgcn_mfma_f32_16x16x32_bf16(aP[rt], bOne, accDen[rt], 0, 0, 0);
        }
        if (cc < 15) {
            #pragma unroll
            for (int nt = 0; nt < 2; nt++)
                #pragma unroll
                for (int rt = 0; rt < 4; rt++) {
                    f32x4 z = {0.f, 0.f, 0.f, 0.f};
                    z = __builtin_amdgcn_mfma_f32_16x16x32_bf16(bK2[nt][0], aQ4[rt][0], z, 0, 0, 0);
                    sv[nt][rt] = __builtin_amdgcn_mfma_f32_16x16x32_bf16(bK2[nt][1], aQ4[rt][1], z, 0, 0, 0);
                }
        }
        __builtin_amdgcn_s_setprio(0);
    }

    // ---- epilogue: rden directly from accDen (no cross-lane reduce) ------
    float rden[4][4];
    #pragma unroll
    for (int rt = 0; rt < 4; rt++)
        #pragma unroll
        for (int reg = 0; reg < 4; reg++)
            rden[rt][reg] = 1.0f / accDen[rt][reg];
    #pragma unroll
    for (int dt = 0; dt < 4; dt++) {
        float ps = 0.f;
        #pragma unroll
        for (int rt = 0; rt < 4; rt++)
            #pragma unroll
            for (int reg = 0; reg < 4; reg++)
                ps += outacc[rt][dt][reg] * rden[rt][reg];
        ps += __shfl_xor(ps, 16);
        ps += __shfl_xor(ps, 32);
        if (quad == 0) redw[dt * 16 + lc] = ps;   // xstage region (dead)
    }
    __syncthreads();
    if (t < 64) {
        float s = 0.f;
        #pragma unroll
        for (int ww = 0; ww < 8; ww++)
            s += *(const float*)(smem + 16 * SLAB + ww * 256 + t * 4);
        pooled[t] = s * (1.0f / 512.0f);
    }
    __syncthreads();
    if (t < NCLASS) {
        float acc = fcb[t];
        #pragma unroll
        for (int d = 0; d < 64; d++) acc += pooled[d] * fcw[t * 64 + d];
        outp[b * NCLASS + t] = acc;
    }
}

// ---------------------------------------------------------------------------
extern "C" void kernel_launch(void* const* d_in, const int* in_sizes, int n_in,
                              void* d_out, int out_size, void* d_ws, size_t ws_size,
                              hipStream_t stream)
{
    const float* x   = (const float*)d_in[0];
    const float* w1  = (const float*)d_in[1];
    const float* cb1 = (const float*)d_in[2];
    const float* g1  = (const float*)d_in[3];
    const float* be1 = (const float*)d_in[4];
    const float* m1  = (const float*)d_in[5];
    const float* v1  = (const float*)d_in[6];
    const float* w2  = (const float*)d_in[7];
    const float* cb2 = (const float*)d_in[8];
    const float* g2  = (const float*)d_in[9];
    const float* be2 = (const float*)d_in[10];
    const float* m2  = (const float*)d_in[11];
    const float* v2  = (const float*)d_in[12];
    const float* wq  = (const float*)d_in[13];
    const float* bq  = (const float*)d_in[14];
    const float* wk  = (const float*)d_in[15];
    const float* bk  = (const float*)d_in[16];
    const float* wv  = (const float*)d_in[17];
    const float* bv  = (const float*)d_in[18];
    const float* fcw = (const float*)d_in[19];
    const float* fcb = (const float*)d_in[20];
    float* out = (float*)d_out;

    char* ws = (char*)d_ws;
    unsigned short* w1p = (unsigned short*)(ws);            // 2048 B
    float*          b1f = (float*)(ws + 2048u);             // 128 B
    float*          b2f = (float*)(ws + 2176u);             // 256 B
    unsigned short* w2p = (unsigned short*)(ws + 2432u);    // 12288 B
    unsigned short* wqp = (unsigned short*)(ws + 14720u);   // 8192 B
    unsigned short* wkp = (unsigned short*)(ws + 22912u);   // 8192 B
    unsigned short* wvp = (unsigned short*)(ws + 31104u);   // 8192 B

    prep_weights<<<dim3(8), 256, 0, stream>>>(w1, cb1, g1, be1, m1, v1,
                                              w2, cb2, g2, be2, m2, v2,
                                              wq, wk, wv,
                                              w1p, b1f, w2p, b2f, wqp, wkp, wvp);
    fused_all<<<dim3(NB), 512, 0, stream>>>(x, w1p, b1f, w2p, b2f,
                                            wqp, wkp, wvp,
                                            bq, bk, bv, fcw, fcb, out);
}